// Round 7
// baseline (14537.770 us; speedup 1.0000x reference)
//
#include <hip/hip_runtime.h>

#define TT 32768
#define BB 32

typedef _Float16 half2_t __attribute__((ext_vector_type(2)));
typedef __fp16   fp16v2  __attribute__((ext_vector_type(2)));

union H2U { half2_t h2; fp16v2 p; unsigned u; _Float16 h[2]; };

__device__ __forceinline__ unsigned packh2(float a, float b) {
    H2U t; t.h[0] = (_Float16)a; t.h[1] = (_Float16)b; return t.u;
}

__device__ __forceinline__ float fdot2u(unsigned wu, unsigned hu, float acc) {
    H2U w, h; w.u = wu; h.u = hu;
    return __builtin_amdgcn_fdot2(w.h2, h.h2, acc, false);
}

__device__ __forceinline__ float rlanef(float v, int lane) {
    return __uint_as_float((unsigned)__builtin_amdgcn_readlane((int)__float_as_uint(v), lane));
}

__device__ __forceinline__ float sigm(float v) {
    return __builtin_amdgcn_rcpf(1.f + __expf(-v));
}
__device__ __forceinline__ float tanh_fast(float v) {
    float e = __expf(2.f * v);
    return 1.f - 2.f * __builtin_amdgcn_rcpf(e + 1.f);  // saturates for large |v|
}

// 4 waves per batch element, one gate per wave (i,f,g,o). Per-wave serial
// chain ~78 instr (vs 185 single-wave round 6): 8 broadcast ds_read_b128 of a
// packed-fp16 h buffer + 32 dot2. One barrier/step (lgkmcnt-only, keeps the
// x-window global prefetch in flight). All waves redundantly compute c,h ->
// no second barrier; each wave owns a private packed-h LDS copy (same-wave
// in-order DS). ~55 VGPR/lane -> no register demotion possible.
__global__ __attribute__((amdgpu_waves_per_eu(1, 1))) __launch_bounds__(256)
void lstm_fused(
    const float* __restrict__ x,      // [T,B]
    const float* __restrict__ W_ih,   // [256]
    const float* __restrict__ W_hh,   // [256,64]  rows: i,f,g,o
    const float* __restrict__ b_ih,   // [256]
    const float* __restrict__ b_hh,   // [256]
    const float* __restrict__ W_out,  // [64]
    const float* __restrict__ b_out,  // [1]
    float* __restrict__ out)          // [T,B]
{
    const int b   = blockIdx.x;
    const int tid = threadIdx.x;
    const int w   = tid >> 6;         // gate index (0=i,1=f,2=g,3=o)
    const int l   = tid & 63;         // h index

    __shared__ float    gbuf[2][4][64];  // gate exchange, double-buffered
    __shared__ unsigned hbuf[4][32];     // per-wave packed-fp16 h copies
    __shared__ float    pbuf[64][65];    // wave-0 output partials (padded)

    // This wave's gate row l of W_hh, packed fp16 pairs: 32 words.
    unsigned wgp[32];
    #pragma unroll
    for (int j = 0; j < 16; ++j) {
        const float4 v = *reinterpret_cast<const float4*>(&W_hh[(w * 64 + l) * 64 + 4 * j]);
        wgp[2 * j]     = packh2(v.x, v.y);
        wgp[2 * j + 1] = packh2(v.z, v.w);
    }

    const float wih  = W_ih[w * 64 + l];
    const float bias = b_ih[w * 64 + l] + b_hh[w * 64 + l];
    const float wo_l = W_out[l];
    const float bo   = b_out[0];

    float c = 0.f, hn = 0.f;

    // init h=0 (all 4 copies) and first x window: lane s holds x[s*B+b]
    if (l < 32) hbuf[w][l] = 0u;
    float xwin  = x[(size_t)l * BB + b];
    float xnext = 0.f;
    __syncthreads();

    #pragma unroll 1
    for (int t = 0; t < TT; ++t) {
        const int s = t & 63;
        const int p = t & 1;

        if (s == 0) {                 // prefetch next x window, 63 steps deep
            int idx = t + 64 + l; if (idx > TT - 1) idx = TT - 1;
            xnext = x[(size_t)idx * BB + b];
        }
        const float xv = rlanef(xwin, s);

        // pre = bias + x*wih + W_row . h   (h from own-wave packed LDS copy)
        float a0 = fmaf(xv, wih, bias), a1 = 0.f, a2 = 0.f, a3 = 0.f;
        const unsigned* hb8 = &hbuf[w][0];
        #pragma unroll
        for (int r = 0; r < 8; ++r) {
            const uint4 hv = *reinterpret_cast<const uint4*>(&hb8[4 * r]);  // broadcast
            a0 = fdot2u(wgp[4 * r + 0], hv.x, a0);
            a1 = fdot2u(wgp[4 * r + 1], hv.y, a1);
            a2 = fdot2u(wgp[4 * r + 2], hv.z, a2);
            a3 = fdot2u(wgp[4 * r + 3], hv.w, a3);
        }
        const float pre = (a0 + a1) + (a2 + a3);
        const float gv  = (w == 2) ? tanh_fast(pre) : sigm(pre);

        gbuf[p][w][l] = gv;
        // writer-side lgkmcnt(0) (write committed) then raw barrier — avoids
        // __syncthreads' vmcnt(0) drain that would kill the x prefetch.
        asm volatile("s_waitcnt lgkmcnt(0)" ::: "memory");
        __builtin_amdgcn_s_barrier();
        __builtin_amdgcn_sched_barrier(0);

        const float iv = gbuf[p][0][l];
        const float fv = gbuf[p][1][l];
        const float gg = gbuf[p][2][l];
        const float ov = gbuf[p][3][l];
        c  = fmaf(fv, c, iv * gg);
        hn = ov * tanh_fast(c);

        // pack (h[2j],h[2j+1]) and store to own-wave copy (even lanes)
        const float hb = __uint_as_float((unsigned)__builtin_amdgcn_mov_dpp(
            (int)__float_as_uint(hn), 0xB1, 0xF, 0xF, true));
        H2U hh; hh.p = __builtin_amdgcn_cvt_pkrtz(hn, hb);
        if ((l & 1) == 0) hbuf[w][l >> 1] = hh.u;

        if (w == 0) {
            pbuf[s][l] = hn * wo_l;   // single-writer, same-wave in-order DS
            if (s == 63) {            // flush window while waves 1-3 run ahead
                float s0 = 0.f, s1 = 0.f, s2 = 0.f, s3 = 0.f;
                #pragma unroll
                for (int j2 = 0; j2 < 16; ++j2) {
                    const float4 v = *reinterpret_cast<const float4*>(&pbuf[l][4 * j2]);
                    s0 += v.x; s1 += v.y; s2 += v.z; s3 += v.w;
                }
                const int tt = (t & ~63) + l;
                out[(size_t)tt * BB + b] = (s0 + s1) + (s2 + s3) + bo + xwin;
            }
        }
        if (s == 63) xwin = xnext;
    }
}

extern "C" void kernel_launch(void* const* d_in, const int* in_sizes, int n_in,
                              void* d_out, int out_size, void* d_ws, size_t ws_size,
                              hipStream_t stream) {
    (void)in_sizes; (void)n_in; (void)d_ws; (void)ws_size; (void)out_size;
    const float* x    = (const float*)d_in[0];
    const float* wih  = (const float*)d_in[1];
    const float* whh  = (const float*)d_in[2];
    const float* bih  = (const float*)d_in[3];
    const float* bhh  = (const float*)d_in[4];
    const float* wout = (const float*)d_in[5];
    const float* bout = (const float*)d_in[6];
    hipLaunchKernelGGL(lstm_fused, dim3(BB), dim3(256), 0, stream,
                       x, wih, whh, bih, bhh, wout, bout, (float*)d_out);
}

// Round 8
// 10488.688 us; speedup vs baseline: 1.3860x; 1.3860x over previous
//
#include <hip/hip_runtime.h>

#define TT 32768
#define BB 32

typedef _Float16 half2_t __attribute__((ext_vector_type(2)));
typedef __fp16   fp16v2  __attribute__((ext_vector_type(2)));

union H2U { half2_t h2; fp16v2 p; unsigned u; _Float16 h[2]; };

static __device__ __forceinline__ unsigned packh2(float a, float b) {
    H2U t; t.h[0] = (_Float16)a; t.h[1] = (_Float16)b; return t.u;
}
static __device__ __forceinline__ float fdot2u(unsigned wu, unsigned hu, float acc) {
    H2U w, h; w.u = wu; h.u = hu;
    return __builtin_amdgcn_fdot2(w.h2, h.h2, acc, false);
}
static __device__ __forceinline__ float rlanef(float v, int lane) {
    return __uint_as_float((unsigned)__builtin_amdgcn_readlane((int)__float_as_uint(v), lane));
}
template <int CTRL>
static __device__ __forceinline__ float dppf(float v) {
    return __uint_as_float((unsigned)__builtin_amdgcn_mov_dpp(
        (int)__float_as_uint(v), CTRL, 0xF, 0xF, true));
}

// 4 waves per batch element; wave w owns h-indices [16w,16w+16); lane l
// computes gate (l&3) of index n=16w+(l>>2). Gate exchange is 3 DPP quad_perm
// ops (intra-quad) -> the round-7 gbuf LDS round-trip (~300cy) is deleted.
// Only cross-wave traffic: packed-fp16 h (32 words, double-buffered), one
// lgkm-only barrier per step. Nonlinearity branch-free via per-lane constants
// (tanh(x) = 2*sigm(2x)-1). Output partials flushed by all 4 waves in parallel
// every 64 steps.
__global__ __attribute__((amdgpu_waves_per_eu(1, 1))) __launch_bounds__(256)
void lstm_fused(
    const float* __restrict__ x,      // [T,B]
    const float* __restrict__ W_ih,   // [256]
    const float* __restrict__ W_hh,   // [256,64]  rows: i,f,g,o
    const float* __restrict__ b_ih,   // [256]
    const float* __restrict__ b_hh,   // [256]
    const float* __restrict__ W_out,  // [64]
    const float* __restrict__ b_out,  // [1]
    float* __restrict__ out)          // [T,B]
{
    const int b   = blockIdx.x;
    const int tid = threadIdx.x;
    const int w   = tid >> 6;         // wave id
    const int l   = tid & 63;         // lane
    const int g   = l & 3;            // gate (0=i,1=f,2=g,3=o)
    const int n   = 16 * w + (l >> 2);// global h index this lane serves

    __shared__ unsigned hbuf[2][32];  // packed fp16 h, double-buffered by t&1
    __shared__ float    pbuf[64][65]; // output partials [step][h-index], padded

    // W_hh row (gate g, output n), packed fp16 pairs: 32 words (~32 VGPR).
    unsigned wgp[32];
    #pragma unroll
    for (int j = 0; j < 16; ++j) {
        const float4 v = *reinterpret_cast<const float4*>(&W_hh[(g * 64 + n) * 64 + 4 * j]);
        wgp[2 * j]     = packh2(v.x, v.y);
        wgp[2 * j + 1] = packh2(v.z, v.w);
    }

    const float wih  = W_ih[g * 64 + n];
    const float bias = b_ih[g * 64 + n] + b_hh[g * 64 + n];
    // branch-free nonlinearity constants: sigm for g!=2, tanh (=2*sigm(2x)-1) for g==2
    const float nm_in  = (g == 2) ? -2.f : -1.f;
    const float nm_out = (g == 2) ?  2.f :  1.f;
    const float na     = (g == 2) ? -1.f :  0.f;
    const float wo_n   = W_out[n];
    const float bo     = b_out[0];

    float c = 0.f, hn = 0.f;

    if (tid < 32) { hbuf[0][tid] = 0u; hbuf[1][tid] = 0u; }
    // x window: lane s holds x[t0+s] (uniform readlane per step)
    float xwin  = x[(size_t)l * BB + b];
    float xnext = 0.f;
    __syncthreads();

    #pragma unroll 1
    for (int t = 0; t < TT; ++t) {
        const int s  = t & 63;
        const int rp = t & 1;

        if (s == 0) {                 // prefetch next x window, 63 steps deep
            int idx = t + 64 + l; if (idx > TT - 1) idx = TT - 1;
            xnext = x[(size_t)idx * BB + b];
        }
        const float xv = rlanef(xwin, s);

        // pre = bias + x*wih + W_row . h   (h broadcast-read, 8x uint4)
        float a0 = fmaf(xv, wih, bias), a1 = 0.f, a2 = 0.f, a3 = 0.f;
        const unsigned* hb = &hbuf[rp][0];
        #pragma unroll
        for (int r = 0; r < 8; ++r) {
            const uint4 hv = *reinterpret_cast<const uint4*>(&hb[4 * r]);
            a0 = fdot2u(wgp[4 * r + 0], hv.x, a0);
            a1 = fdot2u(wgp[4 * r + 1], hv.y, a1);
            a2 = fdot2u(wgp[4 * r + 2], hv.z, a2);
            a3 = fdot2u(wgp[4 * r + 3], hv.w, a3);
        }
        const float pre = (a0 + a1) + (a2 + a3);
        const float gv  = fmaf(__builtin_amdgcn_rcpf(1.f + __expf(nm_in * pre)), nm_out, na);

        // intra-quad gate gather: lane 4k gets f,g,o from quad-mates (i = own gv)
        const float fv = dppf<0x55>(gv);  // quad_perm [1,1,1,1]
        const float gg = dppf<0xAA>(gv);  // quad_perm [2,2,2,2]
        const float ov = dppf<0xFF>(gv);  // quad_perm [3,3,3,3]

        // c,h (valid on lanes with g==0; others compute garbage, never used)
        c = fmaf(fv, c, gv * gg);
        const float th = fmaf(__builtin_amdgcn_rcpf(1.f + __expf(-2.f * c)), 2.f, -1.f);
        hn = ov * th;

        // pack h pair (2m,2m+1): lane 8m takes lane 8m+4's h via row_shl:4
        const float    hs = dppf<0x104>(hn);
        const unsigned pk = (unsigned)__builtin_amdgcn_cvt_pkrtz(hn, hs)[0] |
                            ((unsigned)__builtin_amdgcn_cvt_pkrtz(hn, hs)[1] << 0);
        H2U hh; hh.p = __builtin_amdgcn_cvt_pkrtz(hn, hs);
        if ((l & 7) == 0) hbuf[rp ^ 1][8 * w + (l >> 3)] = hh.u;
        if (g == 0)       pbuf[s][n] = hn * wo_n;

        // lgkm-only barrier (keeps x-window global prefetch in flight)
        asm volatile("s_waitcnt lgkmcnt(0)" ::: "memory");
        __builtin_amdgcn_s_barrier();
        __builtin_amdgcn_sched_barrier(0);

        if (s == 63) {                // all 4 waves flush their 16 rows in parallel
            const int c0 = (g) * 16;  // column chunk within row n
            float s0 = 0.f, s1 = 0.f, s2 = 0.f, s3 = 0.f;
            #pragma unroll
            for (int j2 = 0; j2 < 4; ++j2) {
                const float4 v = *reinterpret_cast<const float4*>(&pbuf[n][c0 + 4 * j2]);
                s0 += v.x; s1 += v.y; s2 += v.z; s3 += v.w;
            }
            float sum = (s0 + s1) + (s2 + s3);
            sum += dppf<0xB1>(sum);   // quad_perm [1,0,3,2]
            sum += dppf<0x4E>(sum);   // quad_perm [2,3,0,1]
            const float xr = __uint_as_float((unsigned)__builtin_amdgcn_ds_bpermute(
                4 * n, (int)__float_as_uint(xwin)));
            if (g == 0) {
                const int tt = (t & ~63) + n;
                out[(size_t)tt * BB + b] = sum + bo + xr;
            }
            xwin = xnext;
        }
    }
}

extern "C" void kernel_launch(void* const* d_in, const int* in_sizes, int n_in,
                              void* d_out, int out_size, void* d_ws, size_t ws_size,
                              hipStream_t stream) {
    (void)in_sizes; (void)n_in; (void)d_ws; (void)ws_size; (void)out_size;
    const float* x    = (const float*)d_in[0];
    const float* wih  = (const float*)d_in[1];
    const float* whh  = (const float*)d_in[2];
    const float* bih  = (const float*)d_in[3];
    const float* bhh  = (const float*)d_in[4];
    const float* wout = (const float*)d_in[5];
    const float* bout = (const float*)d_in[6];
    hipLaunchKernelGGL(lstm_fused, dim3(BB), dim3(256), 0, stream,
                       x, wih, whh, bih, bhh, wout, bout, (float*)d_out);
}

// Round 9
// 10411.918 us; speedup vs baseline: 1.3963x; 1.0074x over previous
//
#include <hip/hip_runtime.h>

#define TT 32768
#define BB 32

typedef _Float16 half2_t __attribute__((ext_vector_type(2)));
union H2U { half2_t h2; unsigned u; _Float16 h[2]; };

static __device__ __forceinline__ unsigned packh2(float a, float b) {
    H2U t; t.h[0] = (_Float16)a; t.h[1] = (_Float16)b; return t.u;
}
static __device__ __forceinline__ float fdot2u(unsigned wu, unsigned hu, float acc) {
    H2U w, h; w.u = wu; h.u = hu;
    return __builtin_amdgcn_fdot2(w.h2, h.h2, acc, false);
}
static __device__ __forceinline__ float rlanef(float v, int lane) {
    return __uint_as_float((unsigned)__builtin_amdgcn_readlane((int)__float_as_uint(v), lane));
}
template <int CTRL>
static __device__ __forceinline__ float dppf(float v) {
    return __uint_as_float((unsigned)__builtin_amdgcn_mov_dpp(
        (int)__float_as_uint(v), CTRL, 0xF, 0xF, true));
}
static __device__ __forceinline__ float exp2_raw(float x) {
    float r; asm("v_exp_f32 %0, %1" : "=v"(r) : "v"(x)); return r;
}

// 4 waves per batch element; wave w owns h-indices [16w,16w+16); lane l
// computes gate (l&3) of index n=16w+(l>>2); gates gathered intra-quad via
// DPP. Exp-prescale folded into weights: pre' = si*pre with si=-log2e
// (sigmoid gates) or -2log2e (g gate), so each nonlinearity is a raw
// v_exp_f32 with no preceding multiply. c kept in scaled domain
// c' = -2log2e*c (i-gate output prescaled by -2log2e), so tanh(c) =
// 2*rcp(1+exp2(c'))-1 with no multiply either. h exchange: producer lanes
// cvt_f16 + ds_write_b16 (no DPP pack); consumers read 8x b128 broadcast.
// lgkmcnt(1) drain on ordinary steps (h-write retired; pbuf write only
// consumed at the s==63 barrier which drains to 0).
__global__ __attribute__((amdgpu_waves_per_eu(1, 1))) __launch_bounds__(256)
void lstm_fused(
    const float* __restrict__ x,      // [T,B]
    const float* __restrict__ W_ih,   // [256]
    const float* __restrict__ W_hh,   // [256,64]  rows: i,f,g,o
    const float* __restrict__ b_ih,   // [256]
    const float* __restrict__ b_hh,   // [256]
    const float* __restrict__ W_out,  // [64]
    const float* __restrict__ b_out,  // [1]
    float* __restrict__ out)          // [T,B]
{
    const int b   = blockIdx.x;
    const int tid = threadIdx.x;
    const int w   = tid >> 6;         // wave id
    const int l   = tid & 63;         // lane
    const int g   = l & 3;            // gate (0=i,1=f,2=g,3=o)
    const int n   = 16 * w + (l >> 2);// h index this lane serves

    __shared__ _Float16 hbuf[2][64];  // fp16 h, double-buffered by t&1
    __shared__ float    pbuf[64][65]; // output partials [step][h-index], padded

    const float L2E = 1.4426950408889634f;
    const float si  = (g == 2) ? (-2.f * L2E) : (-L2E);        // input prescale
    const float nm_out = (g == 0) ? (-2.f * L2E) : ((g == 2) ? 2.f : 1.f);
    const float na     = (g == 2) ? -1.f : 0.f;

    // W_hh row (gate g, output n), prescaled by si, packed fp16 pairs.
    unsigned wgp[32];
    #pragma unroll
    for (int j = 0; j < 16; ++j) {
        const float4 v = *reinterpret_cast<const float4*>(&W_hh[(g * 64 + n) * 64 + 4 * j]);
        wgp[2 * j]     = packh2(si * v.x, si * v.y);
        wgp[2 * j + 1] = packh2(si * v.z, si * v.w);
    }
    const float wih  = si * W_ih[g * 64 + n];
    const float bias = si * (b_ih[g * 64 + n] + b_hh[g * 64 + n]);
    const float wo_n = W_out[n];
    const float bo   = b_out[0];

    float c = 0.f;                    // scaled domain: c' = -2log2e * c_true

    if (tid < 64) { ((unsigned*)hbuf)[tid & 31] = 0u; }   // zero both buffers (64 uints? 2*64*2B=256B=64u)
    if (tid < 64) { ((unsigned*)hbuf)[32 + (tid & 31)] = 0u; }
    // x window: lane s holds x[t0+s]
    float xwin  = x[(size_t)l * BB + b];
    float xnext = 0.f;
    __syncthreads();

    #pragma unroll 1
    for (int t = 0; t < TT; ++t) {
        const int s  = t & 63;
        const int rp = t & 1;

        if (s == 0) {                 // prefetch next x window, 63 steps deep
            int idx = t + 64 + l; if (idx > TT - 1) idx = TT - 1;
            xnext = x[(size_t)idx * BB + b];
        }
        const float xv = rlanef(xwin, s);

        // pre' = bias' + x*wih' + W'_row . h   (h broadcast-read, 8x uint4)
        float a0 = fmaf(xv, wih, bias), a1 = 0.f, a2 = 0.f, a3 = 0.f;
        const unsigned* hb = reinterpret_cast<const unsigned*>(&hbuf[rp][0]);
        #pragma unroll
        for (int r = 0; r < 8; ++r) {
            const uint4 hv = *reinterpret_cast<const uint4*>(&hb[4 * r]);
            a0 = fdot2u(wgp[4 * r + 0], hv.x, a0);
            a1 = fdot2u(wgp[4 * r + 1], hv.y, a1);
            a2 = fdot2u(wgp[4 * r + 2], hv.z, a2);
            a3 = fdot2u(wgp[4 * r + 3], hv.w, a3);
        }
        const float pre = (a0 + a1) + (a2 + a3);
        // gate value: i-lane outputs -2log2e*sigm, f/o: sigm, g: tanh
        const float gv = fmaf(__builtin_amdgcn_rcpf(1.f + exp2_raw(pre)), nm_out, na);

        // intra-quad gate gather (lane g==0 gets f,g,o; own gv is scaled i)
        const float fv = dppf<0x55>(gv);
        const float gg = dppf<0xAA>(gv);
        const float ov = dppf<0xFF>(gv);

        // c' = f*c' + i'*g  (valid on g==0 lanes); tanh(c) = 2*rcp(1+exp2(c'))-1
        c = fmaf(fv, c, gv * gg);
        const float th = fmaf(__builtin_amdgcn_rcpf(1.f + exp2_raw(c)), 2.f, -1.f);
        const float hn = ov * th;

        if (g == 0) {
            hbuf[rp ^ 1][n] = (_Float16)hn;   // cvt_f16 + ds_write_b16
            pbuf[s][n]      = hn * wo_n;      // output partial
        }

        if (s == 63) { asm volatile("s_waitcnt lgkmcnt(0)" ::: "memory"); }
        else         { asm volatile("s_waitcnt lgkmcnt(1)" ::: "memory"); }
        __builtin_amdgcn_s_barrier();
        __builtin_amdgcn_sched_barrier(0);

        if (s == 63) {                // all 4 waves flush their 16 rows in parallel
            const int c0 = g * 16;
            float s0 = 0.f, s1 = 0.f, s2 = 0.f, s3 = 0.f;
            #pragma unroll
            for (int j2 = 0; j2 < 4; ++j2) {
                const float4 v = *reinterpret_cast<const float4*>(&pbuf[n][c0 + 4 * j2]);
                s0 += v.x; s1 += v.y; s2 += v.z; s3 += v.w;
            }
            float sum = (s0 + s1) + (s2 + s3);
            sum += dppf<0xB1>(sum);
            sum += dppf<0x4E>(sum);
            const float xr = __uint_as_float((unsigned)__builtin_amdgcn_ds_bpermute(
                4 * n, (int)__float_as_uint(xwin)));
            if (g == 0) {
                const int tt = (t & ~63) + n;
                out[(size_t)tt * BB + b] = sum + bo + xr;
            }
            xwin = xnext;
        }
    }
}

extern "C" void kernel_launch(void* const* d_in, const int* in_sizes, int n_in,
                              void* d_out, int out_size, void* d_ws, size_t ws_size,
                              hipStream_t stream) {
    (void)in_sizes; (void)n_in; (void)d_ws; (void)ws_size; (void)out_size;
    const float* x    = (const float*)d_in[0];
    const float* wih  = (const float*)d_in[1];
    const float* whh  = (const float*)d_in[2];
    const float* bih  = (const float*)d_in[3];
    const float* bhh  = (const float*)d_in[4];
    const float* wout = (const float*)d_in[5];
    const float* bout = (const float*)d_in[6];
    hipLaunchKernelGGL(lstm_fused, dim3(BB), dim3(256), 0, stream,
                       x, wih, whh, bih, bhh, wout, bout, (float*)d_out);
}

// Round 10
// 10200.056 us; speedup vs baseline: 1.4253x; 1.0208x over previous
//
#include <hip/hip_runtime.h>

#define TT 32768
#define BB 32

typedef _Float16 half2_t __attribute__((ext_vector_type(2)));
union H2U { half2_t h2; unsigned u; _Float16 h[2]; };

static __device__ __forceinline__ unsigned packh2(float a, float b) {
    H2U t; t.h[0] = (_Float16)a; t.h[1] = (_Float16)b; return t.u;
}
static __device__ __forceinline__ float fdot2u(unsigned wu, unsigned hu, float acc) {
    H2U w, h; w.u = wu; h.u = hu;
    return __builtin_amdgcn_fdot2(w.h2, h.h2, acc, false);
}
static __device__ __forceinline__ float rlanef(float v, int lane) {
    return __uint_as_float((unsigned)__builtin_amdgcn_readlane((int)__float_as_uint(v), lane));
}
template <int CTRL>
static __device__ __forceinline__ float dppf(float v) {
    return __uint_as_float((unsigned)__builtin_amdgcn_mov_dpp(
        (int)__float_as_uint(v), CTRL, 0xF, 0xF, true));
}
static __device__ __forceinline__ float exp2_raw(float x) {
    float r; asm("v_exp_f32 %0, %1" : "=v"(r) : "v"(x)); return r;
}

// 8 waves per batch element, split-K. Wave w owns h-indices [8w,8w+8);
// lane l = 8m + 4*kh + g computes gate g of index n=8w+m over k-half kh.
// Per-lane dot: 16 dot2 + 4x b128 LDS reads; k-halves combined via DPP
// (ctrl 0x104 = lane+4, direction verified empirically by rounds 8/9).
// Gates gathered intra-quad via DPP; producers (l%8==0) compute c,h and
// write fp16 h + output partial. One lgkm-only barrier per step; no
// sched_barrier (asm "memory" clobbers on both sides of s_barrier give
// ordering without pinning the schedule). Exp prescales folded into
// weights (round 9); c kept in scaled domain c' = -2log2e*c.
__global__ __launch_bounds__(512, 2) void lstm_fused(
    const float* __restrict__ x,      // [T,B]
    const float* __restrict__ W_ih,   // [256]
    const float* __restrict__ W_hh,   // [256,64]  rows: i,f,g,o
    const float* __restrict__ b_ih,   // [256]
    const float* __restrict__ b_hh,   // [256]
    const float* __restrict__ W_out,  // [64]
    const float* __restrict__ b_out,  // [1]
    float* __restrict__ out)          // [T,B]
{
    const int b   = blockIdx.x;
    const int tid = threadIdx.x;
    const int w   = tid >> 6;         // wave id (0..7)
    const int l   = tid & 63;         // lane
    const int g   = l & 3;            // gate (0=i,1=f,2=g,3=o)
    const int kh  = (l >> 2) & 1;     // k-half (0: k<32, 1: k>=32)
    const int n   = 8 * w + (l >> 3); // h index this lane serves

    __shared__ _Float16 hbuf[2][64];  // fp16 h, double-buffered by t&1
    __shared__ float    pbuf[64][65]; // output partials [step][h-index], padded

    const float L2E = 1.4426950408889634f;
    const float si  = (g == 2) ? (-2.f * L2E) : (-L2E);        // input prescale
    const float nm_out = (g == 0) ? (-2.f * L2E) : ((g == 2) ? 2.f : 1.f);
    const float na     = (g == 2) ? -1.f : 0.f;

    // This lane's k-half of W_hh row (gate g, output n), prescaled, packed fp16.
    unsigned wgp[16];
    #pragma unroll
    for (int j = 0; j < 8; ++j) {
        const float4 v = *reinterpret_cast<const float4*>(
            &W_hh[(g * 64 + n) * 64 + 32 * kh + 4 * j]);
        wgp[2 * j]     = packh2(si * v.x, si * v.y);
        wgp[2 * j + 1] = packh2(si * v.z, si * v.w);
    }
    const float wih  = (kh == 0) ? si * W_ih[g * 64 + n] : 0.f;
    const float bias = (kh == 0) ? si * (b_ih[g * 64 + n] + b_hh[g * 64 + n]) : 0.f;
    const float wo_n = W_out[n];
    const float bo   = b_out[0];

    float c = 0.f;                    // scaled domain: c' = -2log2e * c_true

    if (tid < 64) ((unsigned*)hbuf)[tid] = 0u;   // zero both buffers (64 dwords)
    // x window: lane s holds x[t0+s]
    float xwin  = x[(size_t)l * BB + b];
    float xnext = 0.f;
    __syncthreads();

    #pragma unroll 1
    for (int t = 0; t < TT; ++t) {
        const int s  = t & 63;
        const int rp = t & 1;

        if (s == 0) {                 // prefetch next x window, 63 steps deep
            int idx = t + 64 + l; if (idx > TT - 1) idx = TT - 1;
            xnext = x[(size_t)idx * BB + b];
        }
        const float xv = rlanef(xwin, s);

        // pre'(half) = bias' + x*wih' + W'_half . h_half   (4x b128 reads)
        float a0 = fmaf(xv, wih, bias), a1 = 0.f, a2 = 0.f, a3 = 0.f;
        const unsigned* hb = reinterpret_cast<const unsigned*>(&hbuf[rp][0]) + 16 * kh;
        {
            const uint4 h0 = *reinterpret_cast<const uint4*>(hb);
            const uint4 h1 = *reinterpret_cast<const uint4*>(hb + 4);
            const uint4 h2 = *reinterpret_cast<const uint4*>(hb + 8);
            const uint4 h3 = *reinterpret_cast<const uint4*>(hb + 12);
            a0 = fdot2u(wgp[0],  h0.x, a0); a1 = fdot2u(wgp[1],  h0.y, a1);
            a2 = fdot2u(wgp[2],  h0.z, a2); a3 = fdot2u(wgp[3],  h0.w, a3);
            a0 = fdot2u(wgp[4],  h1.x, a0); a1 = fdot2u(wgp[5],  h1.y, a1);
            a2 = fdot2u(wgp[6],  h1.z, a2); a3 = fdot2u(wgp[7],  h1.w, a3);
            a0 = fdot2u(wgp[8],  h2.x, a0); a1 = fdot2u(wgp[9],  h2.y, a1);
            a2 = fdot2u(wgp[10], h2.z, a2); a3 = fdot2u(wgp[11], h2.w, a3);
            a0 = fdot2u(wgp[12], h3.x, a0); a1 = fdot2u(wgp[13], h3.y, a1);
            a2 = fdot2u(wgp[14], h3.z, a2); a3 = fdot2u(wgp[15], h3.w, a3);
        }
        const float ph  = (a0 + a1) + (a2 + a3);
        const float pre = ph + dppf<0x104>(ph);   // add other k-half (lane+4)
        const float gv  = fmaf(__builtin_amdgcn_rcpf(1.f + exp2_raw(pre)), nm_out, na);

        // intra-quad gate gather (valid on kh==0 quads; consumers are l%8==0)
        const float fv = dppf<0x55>(gv);
        const float gg = dppf<0xAA>(gv);
        const float ov = dppf<0xFF>(gv);

        // c' = f*c' + i'*g ; h = ov*tanh(c) = fma(2ov, rcp(1+exp2(c')), -ov)
        c = fmaf(fv, c, gv * gg);
        const float rc = __builtin_amdgcn_rcpf(1.f + exp2_raw(c));
        const float hn = fmaf(2.f * ov, rc, -ov);

        if ((l & 7) == 0) {
            hbuf[rp ^ 1][n] = (_Float16)hn;   // cvt_f16 + ds_write_b16
            pbuf[s][n]      = hn * wo_n;      // output partial
        }

        asm volatile("s_waitcnt lgkmcnt(0)" ::: "memory");
        __builtin_amdgcn_s_barrier();
        asm volatile("" ::: "memory");

        if (s == 63) {                // all 8 waves flush 8 rows each
            const int r  = 8 * w + (l >> 3);
            const int c8 = (l & 7) * 8;
            const float4 v0 = *reinterpret_cast<const float4*>(&pbuf[r][c8]);
            const float4 v1 = *reinterpret_cast<const float4*>(&pbuf[r][c8 + 4]);
            float sum = ((v0.x + v0.y) + (v0.z + v0.w)) +
                        ((v1.x + v1.y) + (v1.z + v1.w));
            sum += dppf<0xB1>(sum);   // pair
            sum += dppf<0x4E>(sum);   // quad
            sum += dppf<0x104>(sum);  // + other quad (lane+4)
            const float xr = __uint_as_float((unsigned)__builtin_amdgcn_ds_bpermute(
                4 * r, (int)__float_as_uint(xwin)));
            if ((l & 7) == 0) {
                const int tt = (t & ~63) + r;
                out[(size_t)tt * BB + b] = sum + bo + xr;
            }
            xwin = xnext;
        }
    }
}

extern "C" void kernel_launch(void* const* d_in, const int* in_sizes, int n_in,
                              void* d_out, int out_size, void* d_ws, size_t ws_size,
                              hipStream_t stream) {
    (void)in_sizes; (void)n_in; (void)d_ws; (void)ws_size; (void)out_size;
    const float* x    = (const float*)d_in[0];
    const float* wih  = (const float*)d_in[1];
    const float* whh  = (const float*)d_in[2];
    const float* bih  = (const float*)d_in[3];
    const float* bhh  = (const float*)d_in[4];
    const float* wout = (const float*)d_in[5];
    const float* bout = (const float*)d_in[6];
    hipLaunchKernelGGL(lstm_fused, dim3(BB), dim3(512), 0, stream,
                       x, wih, whh, bih, bhh, wout, bout, (float*)d_out);
}

// Round 11
// 9117.864 us; speedup vs baseline: 1.5944x; 1.1187x over previous
//
#include <hip/hip_runtime.h>

#define TT 32768
#define BB 32

typedef _Float16 half2_t __attribute__((ext_vector_type(2)));
union H2U { half2_t h2; unsigned u; _Float16 h[2]; };

static __device__ __forceinline__ unsigned packh2(float a, float b) {
    H2U t; t.h[0] = (_Float16)a; t.h[1] = (_Float16)b; return t.u;
}
static __device__ __forceinline__ float fdot2u(unsigned wu, unsigned hu, float acc) {
    H2U w, h; w.u = wu; h.u = hu;
    return __builtin_amdgcn_fdot2(w.h2, h.h2, acc, false);
}
static __device__ __forceinline__ float rlanef(float v, int lane) {
    return __uint_as_float((unsigned)__builtin_amdgcn_readlane((int)__float_as_uint(v), lane));
}
template <int CTRL>
static __device__ __forceinline__ float dppf(float v) {
    return __uint_as_float((unsigned)__builtin_amdgcn_mov_dpp(
        (int)__float_as_uint(v), CTRL, 0xF, 0xF, true));
}
static __device__ __forceinline__ float exp2_raw(float x) {
    float r; asm("v_exp_f32 %0, %1" : "=v"(r) : "v"(x)); return r;
}

// 8 waves per batch element, split-K (round-10 topology), micro-trimmed:
// - unroll x2 with rp-specialized bodies: LDS addresses loop-invariant,
//   no per-step rp math (less SALU on the CU's single scalar unit).
// - counted drain lgkmcnt(1): hbuf write (emitted first, same-wave DS
//   retires in order) is committed at the barrier; the pbuf partial may
//   lag and is drained by the flush's own lgkmcnt(0)+barrier (1/64 steps).
// - single exec-masked producer region.
__global__ __launch_bounds__(512, 2) void lstm_fused(
    const float* __restrict__ x,      // [T,B]
    const float* __restrict__ W_ih,   // [256]
    const float* __restrict__ W_hh,   // [256,64]  rows: i,f,g,o
    const float* __restrict__ b_ih,   // [256]
    const float* __restrict__ b_hh,   // [256]
    const float* __restrict__ W_out,  // [64]
    const float* __restrict__ b_out,  // [1]
    float* __restrict__ out)          // [T,B]
{
    const int b   = blockIdx.x;
    const int tid = threadIdx.x;
    const int w   = tid >> 6;         // wave id (0..7)
    const int l   = tid & 63;         // lane
    const int g   = l & 3;            // gate (0=i,1=f,2=g,3=o)
    const int kh  = (l >> 2) & 1;     // k-half
    const int n   = 8 * w + (l >> 3); // h index this lane serves

    __shared__ _Float16 hbuf[2][64];  // fp16 h, double-buffered
    __shared__ float    pbuf[64][65]; // output partials [step][h-index], padded

    const float L2E = 1.4426950408889634f;
    const float si  = (g == 2) ? (-2.f * L2E) : (-L2E);
    const float nm_out = (g == 0) ? (-2.f * L2E) : ((g == 2) ? 2.f : 1.f);
    const float na     = (g == 2) ? -1.f : 0.f;

    unsigned wgp[16];
    #pragma unroll
    for (int j = 0; j < 8; ++j) {
        const float4 v = *reinterpret_cast<const float4*>(
            &W_hh[(g * 64 + n) * 64 + 32 * kh + 4 * j]);
        wgp[2 * j]     = packh2(si * v.x, si * v.y);
        wgp[2 * j + 1] = packh2(si * v.z, si * v.w);
    }
    const float wih  = (kh == 0) ? si * W_ih[g * 64 + n] : 0.f;
    const float bias = (kh == 0) ? si * (b_ih[g * 64 + n] + b_hh[g * 64 + n]) : 0.f;
    const float wo_n = W_out[n];
    const float bo   = b_out[0];
    const bool  prod = ((l & 7) == 0);

    float c = 0.f;                    // scaled domain: c' = -2log2e * c_true

    if (tid < 64) ((unsigned*)hbuf)[tid] = 0u;
    float xwin  = x[(size_t)l * BB + b];
    float xnext = 0.f;
    __syncthreads();

    // loop-invariant LDS read bases (one VGPR each; 16B-imm-offset reads)
    const unsigned* hbr0 = reinterpret_cast<const unsigned*>(&hbuf[0][0]) + 16 * kh;
    const unsigned* hbr1 = reinterpret_cast<const unsigned*>(&hbuf[1][0]) + 16 * kh;

#define LSTM_STEP(S, HBR, WRSLOT)                                              \
    do {                                                                       \
        const float xv = rlanef(xwin, (S));                                    \
        float a0 = fmaf(xv, wih, bias), a1 = 0.f, a2 = 0.f, a3 = 0.f;          \
        const uint4 h0 = *reinterpret_cast<const uint4*>((HBR));               \
        const uint4 h1 = *reinterpret_cast<const uint4*>((HBR) + 4);           \
        const uint4 h2 = *reinterpret_cast<const uint4*>((HBR) + 8);           \
        const uint4 h3 = *reinterpret_cast<const uint4*>((HBR) + 12);          \
        a0 = fdot2u(wgp[0],  h0.x, a0); a1 = fdot2u(wgp[1],  h0.y, a1);        \
        a2 = fdot2u(wgp[2],  h0.z, a2); a3 = fdot2u(wgp[3],  h0.w, a3);        \
        a0 = fdot2u(wgp[4],  h1.x, a0); a1 = fdot2u(wgp[5],  h1.y, a1);        \
        a2 = fdot2u(wgp[6],  h1.z, a2); a3 = fdot2u(wgp[7],  h1.w, a3);        \
        a0 = fdot2u(wgp[8],  h2.x, a0); a1 = fdot2u(wgp[9],  h2.y, a1);        \
        a2 = fdot2u(wgp[10], h2.z, a2); a3 = fdot2u(wgp[11], h2.w, a3);        \
        a0 = fdot2u(wgp[12], h3.x, a0); a1 = fdot2u(wgp[13], h3.y, a1);        \
        a2 = fdot2u(wgp[14], h3.z, a2); a3 = fdot2u(wgp[15], h3.w, a3);        \
        const float ph  = (a0 + a1) + (a2 + a3);                               \
        const float pre = ph + dppf<0x104>(ph);                                \
        const float gv  = fmaf(__builtin_amdgcn_rcpf(1.f + exp2_raw(pre)),     \
                               nm_out, na);                                    \
        const float fv = dppf<0x55>(gv);                                       \
        const float gg = dppf<0xAA>(gv);                                       \
        const float ov = dppf<0xFF>(gv);                                       \
        c = fmaf(fv, c, gv * gg);                                              \
        const float rc = __builtin_amdgcn_rcpf(1.f + exp2_raw(c));             \
        const float hn = fmaf(2.f * ov, rc, -ov);                              \
        if (prod) {                                                            \
            hbuf[(WRSLOT)][n] = (_Float16)hn;                                  \
            asm volatile("" ::: "memory");                                     \
            pbuf[(S)][n] = hn * wo_n;                                          \
        }                                                                      \
        asm volatile("s_waitcnt lgkmcnt(1)" ::: "memory");                     \
        __builtin_amdgcn_s_barrier();                                          \
        asm volatile("" ::: "memory");                                         \
    } while (0)

    #pragma unroll 1
    for (int t2 = 0; t2 < TT; t2 += 2) {
        const int sw = t2 & 63;

        if (sw == 0) {                // prefetch next x window, ~62 steps deep
            int idx = t2 + 64 + l; if (idx > TT - 1) idx = TT - 1;
            xnext = x[(size_t)idx * BB + b];
        }

        LSTM_STEP(sw,     hbr0, 1);   // even step: read buf0, write buf1
        LSTM_STEP(sw + 1, hbr1, 0);   // odd  step: read buf1, write buf0

        if (sw == 62) {               // window flush (after step s=63's barrier)
            asm volatile("s_waitcnt lgkmcnt(0)" ::: "memory");
            __builtin_amdgcn_s_barrier();
            asm volatile("" ::: "memory");
            const int r  = 8 * w + (l >> 3);
            const int c8 = (l & 7) * 8;
            const float4 v0 = *reinterpret_cast<const float4*>(&pbuf[r][c8]);
            const float4 v1 = *reinterpret_cast<const float4*>(&pbuf[r][c8 + 4]);
            float sum = ((v0.x + v0.y) + (v0.z + v0.w)) +
                        ((v1.x + v1.y) + (v1.z + v1.w));
            sum += dppf<0xB1>(sum);
            sum += dppf<0x4E>(sum);
            sum += dppf<0x104>(sum);
            const float xr = __uint_as_float((unsigned)__builtin_amdgcn_ds_bpermute(
                4 * r, (int)__float_as_uint(xwin)));
            if (prod) {
                const int tt = (t2 & ~63) + r;
                out[(size_t)tt * BB + b] = sum + bo + xr;
            }
            xwin = xnext;
        }
    }
#undef LSTM_STEP
}

extern "C" void kernel_launch(void* const* d_in, const int* in_sizes, int n_in,
                              void* d_out, int out_size, void* d_ws, size_t ws_size,
                              hipStream_t stream) {
    (void)in_sizes; (void)n_in; (void)d_ws; (void)ws_size; (void)out_size;
    const float* x    = (const float*)d_in[0];
    const float* wih  = (const float*)d_in[1];
    const float* whh  = (const float*)d_in[2];
    const float* bih  = (const float*)d_in[3];
    const float* bhh  = (const float*)d_in[4];
    const float* wout = (const float*)d_in[5];
    const float* bout = (const float*)d_in[6];
    hipLaunchKernelGGL(lstm_fused, dim3(BB), dim3(512), 0, stream,
                       x, wih, whh, bih, bhh, wout, bout, (float*)d_out);
}